// Round 6
// baseline (60.181 us; speedup 1.0000x reference)
//
#include <hip/hip_runtime.h>
#include <math.h>

#define BATCH    4
#define NPTS     8192
#define THREADS  256
#define RTHREADS 1024
#define ROWTILE  128
#define COLTILE  128
#define NCT      8                        // col tiles per block
#define COLSUPER (COLTILE * NCT)          // 1024
#define NROWB    (NPTS / ROWTILE)         // 64
#define NCOLB    (NPTS / COLSUPER)        // 8
#define NMINS    (2 * BATCH * NPTS)       // 65536 (rows: per-gt | cols: per-pred)

// ws layout: [0,512K) G4; [512K,1M) P4; [1M,1.25M) uint mins
#define WS_P4_OFF  (BATCH * NPTS * sizeof(float4))
#define WS_MIN_OFF (2 * BATCH * NPTS * sizeof(float4))
#define INF_BITS   0x7F800000u

// G4[b][n] = (-2gx,-2gy,-2gz,|g|^2)  (rows, gts)
// P4[b][m] = ( px,  py,  pz, |p|^2)  (cols, preds)
__global__ __launch_bounds__(THREADS) void chamfer_pre(const float* __restrict__ preds,
                                                       const float* __restrict__ gts,
                                                       float4* __restrict__ G4,
                                                       float4* __restrict__ P4,
                                                       unsigned int* __restrict__ wsmin) {
    int i = blockIdx.x * THREADS + threadIdx.x;        // 0..65535
    int side = i >> 15;
    int t = i & 32767;
    if (side == 0) {
        float x = gts[3 * t], y = gts[3 * t + 1], z = gts[3 * t + 2];
        G4[t] = make_float4(-2.0f * x, -2.0f * y, -2.0f * z, fmaf(x, x, fmaf(y, y, z * z)));
    } else {
        float x = preds[3 * t], y = preds[3 * t + 1], z = preds[3 * t + 2];
        P4[t] = make_float4(x, y, z, fmaf(x, x, fmaf(y, y, z * z)));
    }
    wsmin[i] = INF_BITS;
}

__global__ __launch_bounds__(THREADS, 4) void chamfer_main(const float4* __restrict__ G4,
                                                           const float4* __restrict__ P4,
                                                           unsigned int* __restrict__ wsmin) {
    const int tileN = blockIdx.x;          // row tile
    const int csup  = blockIdx.y;          // col super-tile (1024 cols)
    const int b     = blockIdx.z;

    __shared__ float4 GL[ROWTILE];
    __shared__ float4 PLB[2][COLTILE];     // double-buffered col tile
    __shared__ float  colbuf[2][4][COLTILE];

    const int t = threadIdx.x, tx = t & 15, ty = t >> 4, wv = t >> 6;
    const size_t gbase = (size_t)b * NPTS;
    const size_t pbase = gbase + (size_t)csup * COLSUPER;

    // prologue: stage G rows (threads 0..127) + first P tile (threads 128..255)
    if (t < ROWTILE) {
        GL[t] = G4[gbase + (size_t)tileN * ROWTILE + t];
    } else {
        PLB[0][t - ROWTILE] = P4[pbase + (t - ROWTILE)];
    }
    __syncthreads();

    // u' = |g|^2 - 2 g.p  (fma chain ends at gw); P = u' + pw
    float gx[8], gy[8], gz[8], gw[8], rmin[8];
#pragma unroll
    for (int i = 0; i < 8; ++i) {
        float4 g = GL[ty + 16 * i];        // 16-lane broadcast, conflict-free
        gx[i] = g.x; gy[i] = g.y; gz[i] = g.z; gw[i] = g.w;
        rmin[i] = INFINITY;
    }

    for (int ct = 0; ct < NCT; ++ct) {
        const int cur = ct & 1;

        // T14 split-stage: issue next tile's global load BEFORE compute
        float4 stage;
        const bool do_stage = (ct + 1 < NCT) && (t < COLTILE);
        if (do_stage) stage = P4[pbase + (size_t)(ct + 1) * COLTILE + t];

        float px[8], py[8], pz[8], pw[8], cmin[8];
#pragma unroll
        for (int j = 0; j < 8; ++j) {
            float4 p = PLB[cur][tx + 16 * j];   // 2-way at worst -> free
            px[j] = p.x; py[j] = p.y; pz[j] = p.z; pw[j] = p.w;
            cmin[j] = INFINITY;
        }

        // 8x8 patch, 2x2 quads: 12 fma + 4 add + 4 min3 per 4 pairs = 5 ops/pair
#pragma unroll
        for (int j = 0; j < 8; j += 2) {
#pragma unroll
            for (int i = 0; i < 8; i += 2) {
                float u00, u01, u10, u11;
                { float s = fmaf(gz[i  ], pz[j  ], gw[i  ]); s = fmaf(gy[i  ], py[j  ], s); u00 = fmaf(gx[i  ], px[j  ], s); }
                { float s = fmaf(gz[i+1], pz[j  ], gw[i+1]); s = fmaf(gy[i+1], py[j  ], s); u01 = fmaf(gx[i+1], px[j  ], s); }
                { float s = fmaf(gz[i  ], pz[j+1], gw[i  ]); s = fmaf(gy[i  ], py[j+1], s); u10 = fmaf(gx[i  ], px[j+1], s); }
                { float s = fmaf(gz[i+1], pz[j+1], gw[i+1]); s = fmaf(gy[i+1], py[j+1], s); u11 = fmaf(gx[i+1], px[j+1], s); }
                float t00 = u00 + pw[j  ], t01 = u01 + pw[j  ];
                float t10 = u10 + pw[j+1], t11 = u11 + pw[j+1];
                rmin[i  ] = fminf(fminf(rmin[i  ], t00), t10);   // -> v_min3
                rmin[i+1] = fminf(fminf(rmin[i+1], t01), t11);
                cmin[j  ] = fminf(fminf(cmin[j  ], u00), u01);   // raw u'; pw added per tile
                cmin[j+1] = fminf(fminf(cmin[j+1], u10), u11);
            }
        }

        // col reduce: +pw once per tile, then xor16/32 (lanes in chain share tx)
#pragma unroll
        for (int j = 0; j < 8; ++j) {
            float c = cmin[j] + pw[j];
            c = fminf(c, __shfl_xor(c, 16, 64));
            c = fminf(c, __shfl_xor(c, 32, 64));
            if ((t & 63) < 16) colbuf[cur][wv][tx + 16 * j] = c;
        }

        // T14 split-stage: ds_write AFTER compute (latency hidden underneath)
        if (do_stage) PLB[cur ^ 1][t] = stage;

        __syncthreads();                   // PLB[cur^1] + colbuf[cur] ready

        if (t < COLTILE) {
            float v = fminf(fminf(colbuf[cur][0][t], colbuf[cur][1][t]),
                            fminf(colbuf[cur][2][t], colbuf[cur][3][t]));
            v = fmaxf(v, 0.0f);            // keep uint ordering valid
            atomicMin(&wsmin[(size_t)(BATCH + b) * NPTS + (size_t)csup * COLSUPER + (size_t)ct * COLTILE + t],
                      __float_as_uint(v)); // exact & deterministic
        }
    }

    // row reduce: xor 1,2,4,8 collapses the 16-lane tx group; once per block
#pragma unroll
    for (int i = 0; i < 8; ++i) {
        float r = rmin[i];
        r = fminf(r, __shfl_xor(r, 1, 64));
        r = fminf(r, __shfl_xor(r, 2, 64));
        r = fminf(r, __shfl_xor(r, 4, 64));
        r = fminf(r, __shfl_xor(r, 8, 64));
        if (tx == 0) {
            float v = fmaxf(r, 0.0f);
            atomicMin(&wsmin[gbase + (size_t)tileN * ROWTILE + ty + 16 * i],
                      __float_as_uint(v));
        }
    }
}

__global__ __launch_bounds__(RTHREADS) void chamfer_reduce(const unsigned int* __restrict__ wsmin,
                                                           float* __restrict__ out) {
    const float4* __restrict__ v = (const float4*)wsmin;  // bits are valid floats (>=0)
    float s = 0.0f;
    int i = threadIdx.x;
#pragma unroll
    for (int it = 0; it < NMINS / 4 / RTHREADS; ++it, i += RTHREADS) {
        float4 a = v[i];
        s += (a.x + a.y) + (a.z + a.w);
    }
    for (int off = 32; off; off >>= 1) s += __shfl_down(s, off, 64);
    __shared__ float sm[RTHREADS / 64];
    if ((threadIdx.x & 63) == 0) sm[threadIdx.x >> 6] = s;
    __syncthreads();
    if (threadIdx.x == 0) {
        float tt = 0.0f;
#pragma unroll
        for (int w = 0; w < RTHREADS / 64; ++w) tt += sm[w];
        out[0] = tt / (float)NPTS;  // sum(mins1)/M + sum(mins2)/N, M=N=NPTS
    }
}

extern "C" void kernel_launch(void* const* d_in, const int* in_sizes, int n_in,
                              void* d_out, int out_size, void* d_ws, size_t ws_size,
                              hipStream_t stream) {
    const float* preds = (const float*)d_in[0];
    const float* gts   = (const float*)d_in[1];
    float* out = (float*)d_out;
    float4* G4 = (float4*)d_ws;
    float4* P4 = (float4*)((char*)d_ws + WS_P4_OFF);
    unsigned int* wsmin = (unsigned int*)((char*)d_ws + WS_MIN_OFF);

    chamfer_pre<<<NMINS / THREADS, THREADS, 0, stream>>>(preds, gts, G4, P4, wsmin);

    dim3 grid(NROWB, NCOLB, BATCH);
    chamfer_main<<<grid, THREADS, 0, stream>>>(G4, P4, wsmin);

    chamfer_reduce<<<1, RTHREADS, 0, stream>>>(wsmin, out);
}